// Round 7
// baseline (368.768 us; speedup 1.0000x reference)
//
#include <hip/hip_runtime.h>
#include <hip/hip_bf16.h>

// B=8,G=16,N=1024,C=256.
// R12: persistent 4-tile blocks + in-block pipeline.
//  Grid = (bg, ntgroup) = 128*4 = 512 blocks x 512 thr (exactly 2/CU).
//  Per block: B-frags (16x bf16x8, fragment-major WbT) loaded ONCE; 4 n-tiles
//  processed with double-buffered LDS (xs[2], vsm[2]); tile i+1 x/v loads
//  issued (fenced, two 4-float4 halves to cap VGPR) under tile i's
//  MFMA+phaseB; one lgkm-only barrier per tile. Z/S accumulate in regs
//  across tiles -> ONE atomicAdd per col per block (4x fewer).
//  MFMA/phaseB split in two m-halves so acc live-range is 16 VGPRs;
//  peak pressure ~120 < 128 cap of launch_bounds(512,4).
// wfc_cvt / vn_linear / ws layout unchanged (passing since R7).

#define NQ 1024
#define CQ 256
#define RT 64           // rows per tile
#define XS2 264         // xs row stride (bf16 elems): 528 B (16B-mult)
#define WB_OFF 131072   // ws float offset of bf16 Wfc (after 512 KB partials)

typedef __attribute__((ext_vector_type(8))) short bf16x8;
typedef __attribute__((ext_vector_type(4))) float f32x4;

__device__ __forceinline__ ushort2 pk2(float a, float b) {
    __hip_bfloat162 h = __float22bfloat162_rn(make_float2(a, b));  // v_cvt_pk_bf16_f32
    ushort2 r;
    __builtin_memcpy(&r, &h, sizeof(r));
    return r;
}
__device__ __forceinline__ float bf2f(ushort h) {
    union { unsigned u; float f; } v; v.u = ((unsigned)h) << 16;
    return v.f;
}

// lgkm-only barrier: LDS writes visible, global loads stay in flight.
__device__ __forceinline__ void bar_lgkm() {
    __builtin_amdgcn_sched_barrier(0);
    asm volatile("s_waitcnt lgkmcnt(0)" ::: "memory");
    __builtin_amdgcn_sched_barrier(0);
    __builtin_amdgcn_s_barrier();
    __builtin_amdgcn_sched_barrier(0);
}

// ---- kernel 1: Wfc fp32 -> bf16 fragment-major WbT[k>>3][col][k&7] ----
__global__ __launch_bounds__(256)
void wfc_cvt(const float* __restrict__ Wfc, ushort* __restrict__ WbT) {
    const int i = blockIdx.x * 256 + threadIdx.x;   // 16384 threads x 4 floats
    const int o = i >> 6;            // output col (Wfc row) 0..255
    const int k4 = (i & 63) * 4;     // k start 0..252
    float4 v = *reinterpret_cast<const float4*>(Wfc + (size_t)o * CQ + k4);
    ushort2 a0 = pk2(v.x, v.y), a1 = pk2(v.z, v.w);
    ushort4 pk = { a0.x, a0.y, a1.x, a1.y };
    *reinterpret_cast<ushort4*>(WbT + ((size_t)(k4 >> 3) * CQ + o) * 8 + (k4 & 7)) = pk;
}

// ---- kernel 2: fused q=x@Wfc^T, e=exp(q), partial Z/S accumulation ----
__global__ __launch_bounds__(512, 4)
void attn_pool_partial(const float* __restrict__ x, const float* __restrict__ vs,
                       const ushort* __restrict__ WbT, float* __restrict__ ws) {
    __shared__ __align__(16) ushort xs[2][RT * XS2];  // 2 x 33792 B
    __shared__ __align__(16) float  vsm[2][RT * 3];   // 2 x 768 B

    const int t = threadIdx.x;                     // 0..511
    const int id = blockIdx.x;                     // 0..511
    const int bg = id >> 2;
    const int ntg = id & 3;
    const int nb = ntg * 4 * RT;                   // this block's rows nb..nb+255

    const int w = t >> 6, lane = t & 63;
    const int quad = lane >> 4, l16 = lane & 15;
    const int bcol0 = w * 32 + l16;                // wave w owns cols w*32..w*32+31
    const bool vload = (t < 48);

    const float* xb = x + (size_t)bg * NQ * CQ;
    const float* vb = vs + (size_t)bg * NQ * 3;

    // staging map: LA[p] = row (p*8 + w), 16B at col lane*4 (one row per wave-load)

    // ---- prologue: B-frags issued first (L2-hot, stay in regs all block) ----
    bf16x8 Bf0[8], Bf1[8];
    #pragma unroll
    for (int ks = 0; ks < 8; ++ks) {
        const size_t fo = (size_t)(ks * 4 + quad) * (CQ * 8);
        Bf0[ks] = *reinterpret_cast<const bf16x8*>(WbT + fo + (size_t)bcol0 * 8);
        Bf1[ks] = *reinterpret_cast<const bf16x8*>(WbT + fo + (size_t)(bcol0 + 16) * 8);
    }
    __builtin_amdgcn_sched_barrier(0);

    // ---- tile 0 loads ----
    {
        float4 vreg;
        if (vload) vreg = reinterpret_cast<const float4*>(vb + (size_t)nb * 3)[t];
        float4 L[8];
        #pragma unroll
        for (int p = 0; p < 8; ++p) {
            const int row = p * 8 + w;
            L[p] = *reinterpret_cast<const float4*>(
                xb + (size_t)(nb + row) * CQ + lane * 4);
        }
        __builtin_amdgcn_sched_barrier(0);
        #pragma unroll
        for (int p = 0; p < 8; ++p) {
            const int row = p * 8 + w;
            ushort2 a0 = pk2(L[p].x, L[p].y), a1 = pk2(L[p].z, L[p].w);
            ushort4 pk = { a0.x, a0.y, a1.x, a1.y };
            *reinterpret_cast<ushort4*>(&xs[0][row * XS2 + lane * 4]) = pk;
        }
        if (vload) reinterpret_cast<float4*>(vsm[0])[t] = vreg;
    }
    bar_lgkm();

    // running partials across all 4 tiles
    float rZ[2] = {0.f, 0.f}, rS0[2] = {0.f, 0.f}, rS1[2] = {0.f, 0.f}, rS2[2] = {0.f, 0.f};

    #pragma unroll
    for (int i = 0; i < 4; ++i) {
        const int cur = i & 1, nxt = cur ^ 1;
        const bool pf = (i < 3);
        const size_t nnb = (size_t)(nb + (i + 1) * RT);   // next tile row base

        // ---- issue first half of next-tile loads (rows 0..31) + v ----
        float4 LAa[4], LAb[4], vreg;
        if (pf) {
            if (vload) vreg = reinterpret_cast<const float4*>(vb + nnb * 3)[t];
            #pragma unroll
            for (int p = 0; p < 4; ++p) {
                const int row = p * 8 + w;
                LAa[p] = *reinterpret_cast<const float4*>(
                    xb + (nnb + row) * CQ + lane * 4);
            }
        }
        __builtin_amdgcn_sched_barrier(0);

        // ================= half 0: m = 0,1 =================
        {
            f32x4 acc[2][2];
            #pragma unroll
            for (int mi = 0; mi < 2; ++mi)
                #pragma unroll
                for (int ci = 0; ci < 2; ++ci) acc[mi][ci] = (f32x4){0.f, 0.f, 0.f, 0.f};
            __builtin_amdgcn_s_setprio(1);
            #pragma unroll
            for (int ks = 0; ks < 8; ++ks) {
                const int kk = ks * 32 + quad * 8;
                #pragma unroll
                for (int mi = 0; mi < 2; ++mi) {
                    bf16x8 a = *reinterpret_cast<const bf16x8*>(
                        &xs[cur][(mi * 16 + l16) * XS2 + kk]);
                    acc[mi][0] = __builtin_amdgcn_mfma_f32_16x16x32_bf16(a, Bf0[ks], acc[mi][0], 0, 0, 0);
                    acc[mi][1] = __builtin_amdgcn_mfma_f32_16x16x32_bf16(a, Bf1[ks], acc[mi][1], 0, 0, 0);
                }
            }
            __builtin_amdgcn_s_setprio(0);
            // phase B for rows 0..31
            #pragma unroll
            for (int mi = 0; mi < 2; ++mi) {
                const int rbase = mi * 16 + quad * 4;
                float v0[4], v1[4], v2[4];
                #pragma unroll
                for (int r = 0; r < 4; ++r) {
                    v0[r] = vsm[cur][(rbase + r) * 3 + 0];
                    v1[r] = vsm[cur][(rbase + r) * 3 + 1];
                    v2[r] = vsm[cur][(rbase + r) * 3 + 2];
                }
                #pragma unroll
                for (int ci = 0; ci < 2; ++ci) {
                    const int xc = w * 32 + ci * 16 + l16;
                    #pragma unroll
                    for (int r = 0; r < 4; ++r) {
                        float e = __expf(acc[mi][ci][r]);
                        float xv = bf2f(xs[cur][(rbase + r) * XS2 + xc]);
                        rZ[ci] += e;
                        float p = e * xv;
                        rS0[ci] = fmaf(p, v0[r], rS0[ci]);
                        rS1[ci] = fmaf(p, v1[r], rS1[ci]);
                        rS2[ci] = fmaf(p, v2[r], rS2[ci]);
                    }
                }
            }
        }

        // ---- cvt.a: write next-tile rows 0..31 (waits LAa+v; counted) ----
        if (pf) {
            #pragma unroll
            for (int p = 0; p < 4; ++p) {
                const int row = p * 8 + w;
                ushort2 a0 = pk2(LAa[p].x, LAa[p].y), a1 = pk2(LAa[p].z, LAa[p].w);
                ushort4 pk = { a0.x, a0.y, a1.x, a1.y };
                *reinterpret_cast<ushort4*>(&xs[nxt][row * XS2 + lane * 4]) = pk;
            }
            if (vload) reinterpret_cast<float4*>(vsm[nxt])[t] = vreg;
        }
        __builtin_amdgcn_sched_barrier(0);

        // ---- issue second half of next-tile loads (rows 32..63) ----
        if (pf) {
            #pragma unroll
            for (int p = 0; p < 4; ++p) {
                const int row = 32 + p * 8 + w;
                LAb[p] = *reinterpret_cast<const float4*>(
                    xb + (nnb + row) * CQ + lane * 4);
            }
        }
        __builtin_amdgcn_sched_barrier(0);

        // ================= half 1: m = 2,3 =================
        {
            f32x4 acc[2][2];
            #pragma unroll
            for (int mi = 0; mi < 2; ++mi)
                #pragma unroll
                for (int ci = 0; ci < 2; ++ci) acc[mi][ci] = (f32x4){0.f, 0.f, 0.f, 0.f};
            __builtin_amdgcn_s_setprio(1);
            #pragma unroll
            for (int ks = 0; ks < 8; ++ks) {
                const int kk = ks * 32 + quad * 8;
                #pragma unroll
                for (int mi = 0; mi < 2; ++mi) {
                    bf16x8 a = *reinterpret_cast<const bf16x8*>(
                        &xs[cur][((mi + 2) * 16 + l16) * XS2 + kk]);
                    acc[mi][0] = __builtin_amdgcn_mfma_f32_16x16x32_bf16(a, Bf0[ks], acc[mi][0], 0, 0, 0);
                    acc[mi][1] = __builtin_amdgcn_mfma_f32_16x16x32_bf16(a, Bf1[ks], acc[mi][1], 0, 0, 0);
                }
            }
            __builtin_amdgcn_s_setprio(0);
            // phase B for rows 32..63
            #pragma unroll
            for (int mi = 0; mi < 2; ++mi) {
                const int rbase = (mi + 2) * 16 + quad * 4;
                float v0[4], v1[4], v2[4];
                #pragma unroll
                for (int r = 0; r < 4; ++r) {
                    v0[r] = vsm[cur][(rbase + r) * 3 + 0];
                    v1[r] = vsm[cur][(rbase + r) * 3 + 1];
                    v2[r] = vsm[cur][(rbase + r) * 3 + 2];
                }
                #pragma unroll
                for (int ci = 0; ci < 2; ++ci) {
                    const int xc = w * 32 + ci * 16 + l16;
                    #pragma unroll
                    for (int r = 0; r < 4; ++r) {
                        float e = __expf(acc[mi][ci][r]);
                        float xv = bf2f(xs[cur][(rbase + r) * XS2 + xc]);
                        rZ[ci] += e;
                        float p = e * xv;
                        rS0[ci] = fmaf(p, v0[r], rS0[ci]);
                        rS1[ci] = fmaf(p, v1[r], rS1[ci]);
                        rS2[ci] = fmaf(p, v2[r], rS2[ci]);
                    }
                }
            }
        }

        // ---- cvt.b: write next-tile rows 32..63, then barrier ----
        if (pf) {
            #pragma unroll
            for (int p = 0; p < 4; ++p) {
                const int row = 32 + p * 8 + w;
                ushort2 a0 = pk2(LAb[p].x, LAb[p].y), a1 = pk2(LAb[p].z, LAb[p].w);
                ushort4 pk = { a0.x, a0.y, a1.x, a1.y };
                *reinterpret_cast<ushort4*>(&xs[nxt][row * XS2 + lane * 4]) = pk;
            }
            bar_lgkm();
        }
    }

    // ---- reduce over quads and ONE atomicAdd per col per block ----
    #pragma unroll
    for (int ci = 0; ci < 2; ++ci) {
        float z = rZ[ci], s0 = rS0[ci], s1 = rS1[ci], s2 = rS2[ci];
        #pragma unroll
        for (int off = 16; off < 64; off <<= 1) {
            z  += __shfl_xor(z,  off);
            s0 += __shfl_xor(s0, off);
            s1 += __shfl_xor(s1, off);
            s2 += __shfl_xor(s2, off);
        }
        if (quad == 0) {
            const int col = w * 32 + ci * 16 + l16;
            float* p = ws + ((size_t)bg * CQ + col) * 4;
            atomicAdd(&p[0], z);
            atomicAdd(&p[1], s0);
            atomicAdd(&p[2], s1);
            atomicAdd(&p[3], s2);
        }
    }
}

// ---- kernel 3: out[bg][o][d] = sum_c Wvn[o][c] * S[bg][c][d] / Z[bg][c] ----
__global__ __launch_bounds__(256, 4)
void vn_linear(const float* __restrict__ ws, const float* __restrict__ Wvn,
               float* __restrict__ out) {
    __shared__ float Tsm[CQ][3];
    const int bg = blockIdx.x, t = threadIdx.x;
    {
        f32x4 z4 = *reinterpret_cast<const f32x4*>(ws + ((size_t)bg * CQ + t) * 4);
        float inv = 1.f / z4[0];
        Tsm[t][0] = z4[1] * inv;
        Tsm[t][1] = z4[2] * inv;
        Tsm[t][2] = z4[3] * inv;
    }
    __syncthreads();
    const float* wr = Wvn + (size_t)t * CQ;
    float a0 = 0.f, a1 = 0.f, a2 = 0.f;
    #pragma unroll
    for (int c = 0; c < CQ; c += 4) {
        float4 w4 = *reinterpret_cast<const float4*>(wr + c);
        a0 += w4.x * Tsm[c + 0][0] + w4.y * Tsm[c + 1][0]
            + w4.z * Tsm[c + 2][0] + w4.w * Tsm[c + 3][0];
        a1 += w4.x * Tsm[c + 0][1] + w4.y * Tsm[c + 1][1]
            + w4.z * Tsm[c + 2][1] + w4.w * Tsm[c + 3][1];
        a2 += w4.x * Tsm[c + 0][2] + w4.y * Tsm[c + 1][2]
            + w4.z * Tsm[c + 2][2] + w4.w * Tsm[c + 3][2];
    }
    float* op = out + ((size_t)bg * CQ + t) * 3;
    op[0] = a0; op[1] = a1; op[2] = a2;
}

extern "C" void kernel_launch(void* const* d_in, const int* in_sizes, int n_in,
                              void* d_out, int out_size, void* d_ws, size_t ws_size,
                              hipStream_t stream) {
    const float* x   = (const float*)d_in[0];  // [8,16,1024,256]
    const float* vs  = (const float*)d_in[1];  // [8,16,1,1024,3]
    const float* Wfc = (const float*)d_in[2];  // [256,256]
    // d_in[3] = b_fc: constant along softmax axis n -> no effect, unused
    const float* Wvn = (const float*)d_in[4];  // [256,256]
    float* out = (float*)d_out;                // [8,16,256,3]
    float* ws  = (float*)d_ws;                 // 512 KB partials + 128 KB bf16 Wfc

    ushort* WbT = (ushort*)(ws + WB_OFF);

    (void)hipMemsetAsync(ws, 0, (size_t)128 * CQ * 4 * sizeof(float), stream);
    wfc_cvt<<<dim3(64), dim3(256), 0, stream>>>(Wfc, WbT);
    attn_pool_partial<<<dim3(512), dim3(512), 0, stream>>>(x, vs, WbT, ws);
    vn_linear<<<dim3(128), dim3(256), 0, stream>>>(ws, Wvn, out);
}

// Round 8
// 313.797 us; speedup vs baseline: 1.1752x; 1.1752x over previous
//
#include <hip/hip_runtime.h>
#include <hip/hip_bf16.h>

// B=8,G=16,N=1024,C=256.
// R13: persistent blocks + global_load_lds direct HBM->LDS staging.
//  R12's spill (WRITE_SIZE 334MB scratch) came from holding staged x in VGPRs
//  across compute. Fix: stage via __builtin_amdgcn_global_load_lds (no regs),
//  fp32 in LDS, cvt->bf16 at fragment-read time (4 cvt_pk/frag).
//  Grid = 512 blocks (2/CU) x 512 thr; each block: 1 bg x 8 tiles of 32 rows.
//  Per tile: issue 4 gload_lds/wave for tile i+1 (pre-swizzled global src,
//  linear LDS dest, T21/m173), compute tile i, one vmcnt(0)+barrier. Loads
//  fly under the whole compute -> HBM stream stays busy across barriers.
//  B-frags (64 VGPR) loaded once/block, amortized 8x; v-slab (3KB) once.
// wfc_cvt / vn_linear / ws layout unchanged (passing since R7).

#define NQ 1024
#define CQ 256
#define RT 32            // rows per tile
#define TILES 8          // tiles per block (8*32 = 256 rows/block)
#define WB_OFF 131072    // ws float offset of bf16 Wfc (after 512 KB partials)

typedef __attribute__((ext_vector_type(8))) short bf16x8;
typedef __attribute__((ext_vector_type(4))) float f32x4;

__device__ __forceinline__ ushort2 pk2(float a, float b) {
    __hip_bfloat162 h = __float22bfloat162_rn(make_float2(a, b));  // v_cvt_pk_bf16_f32
    ushort2 r;
    __builtin_memcpy(&r, &h, sizeof(r));
    return r;
}

// async 16B HBM->LDS; per-lane global src, wave-uniform LDS base (+lane*16 by HW)
__device__ __forceinline__ void gload16(const float* g, float* l) {
    __builtin_amdgcn_global_load_lds(
        (const __attribute__((address_space(1))) unsigned int*)g,
        (__attribute__((address_space(3))) unsigned int*)l, 16, 0, 0);
}

// ---- kernel 1: Wfc fp32 -> bf16 fragment-major WbT[k>>3][col][k&7] ----
__global__ __launch_bounds__(256)
void wfc_cvt(const float* __restrict__ Wfc, ushort* __restrict__ WbT) {
    const int i = blockIdx.x * 256 + threadIdx.x;   // 16384 threads x 4 floats
    const int o = i >> 6;            // output col (Wfc row) 0..255
    const int k4 = (i & 63) * 4;     // k start 0..252
    float4 v = *reinterpret_cast<const float4*>(Wfc + (size_t)o * CQ + k4);
    ushort2 a0 = pk2(v.x, v.y), a1 = pk2(v.z, v.w);
    ushort4 pk = { a0.x, a0.y, a1.x, a1.y };
    *reinterpret_cast<ushort4*>(WbT + ((size_t)(k4 >> 3) * CQ + o) * 8 + (k4 & 7)) = pk;
}

// ---- kernel 2: fused q=x@Wfc^T, e=exp(q), partial Z/S accumulation ----
__global__ __launch_bounds__(512, 4)
void attn_pool_partial(const float* __restrict__ x, const float* __restrict__ vs,
                       const ushort* __restrict__ WbT, float* __restrict__ ws) {
    __shared__ __align__(16) float xsf[2][RT * CQ];     // 2 x 32 KB, fp32, swizzled cols
    __shared__ __align__(16) float vsm[TILES * RT * 3]; // 3 KB: whole slab's v

    const int t = threadIdx.x;                     // 0..511
    const int id = blockIdx.x;                     // 0..511
    const int bg = id >> 2;
    const int ntg = id & 3;
    const int nb = ntg * (TILES * RT);             // block's 256-row slab

    const int w = t >> 6, lane = t & 63;
    const int quad = lane >> 4, l16 = lane & 15;
    const int sxA = (l16 & 7) << 2;                // fragment-read swizzle (elems)

    const float* xb = x + (size_t)bg * NQ * CQ;
    const float* vb = vs + (size_t)bg * NQ * 3;

    // ---- prologue group 1: B-fragments (L2-hot, live all block) ----
    bf16x8 Bf0[8], Bf1[8];
    const int bcol0 = w * 32 + l16;
    #pragma unroll
    for (int ks = 0; ks < 8; ++ks) {
        const size_t fo = (size_t)(ks * 4 + quad) * (CQ * 8);
        Bf0[ks] = *reinterpret_cast<const bf16x8*>(WbT + fo + (size_t)bcol0 * 8);
        Bf1[ks] = *reinterpret_cast<const bf16x8*>(WbT + fo + (size_t)(bcol0 + 16) * 8);
    }
    __builtin_amdgcn_sched_barrier(0);

    // ---- prologue group 2: v slab (256 rows x 3 = 768 floats) ----
    const bool vload = (t < 192);
    float4 vreg;
    if (vload) vreg = reinterpret_cast<const float4*>(vb + (size_t)nb * 3)[t];
    __builtin_amdgcn_sched_barrier(0);

    // ---- prologue group 3: stage tile 0 (async, no regs) ----
    #pragma unroll
    for (int p = 0; p < 4; ++p) {
        const int row = p * 8 + w;
        gload16(xb + (size_t)(nb + row) * CQ + (((lane * 4) ^ (w << 2))),
                &xsf[0][row * CQ]);
    }
    __builtin_amdgcn_sched_barrier(0);
    if (vload) reinterpret_cast<float4*>(vsm)[t] = vreg;
    __builtin_amdgcn_sched_barrier(0);
    asm volatile("s_waitcnt vmcnt(0) lgkmcnt(0)" ::: "memory");
    __builtin_amdgcn_sched_barrier(0);
    __builtin_amdgcn_s_barrier();
    __builtin_amdgcn_sched_barrier(0);

    // running partials across all 8 tiles
    float rZ[2] = {0.f, 0.f}, rS0[2] = {0.f, 0.f}, rS1[2] = {0.f, 0.f}, rS2[2] = {0.f, 0.f};

    for (int i = 0; i < TILES; ++i) {
        const int cur = i & 1;
        const float* xsb = xsf[cur];

        // ---- issue next tile's staging (flies under this tile's compute) ----
        if (i < TILES - 1) {
            const size_t gr = (size_t)(nb + (i + 1) * RT);
            float* dst = xsf[cur ^ 1];
            #pragma unroll
            for (int p = 0; p < 4; ++p) {
                const int row = p * 8 + w;
                gload16(xb + (gr + row) * CQ + (((lane * 4) ^ (w << 2))),
                        dst + row * CQ);
            }
        }
        __builtin_amdgcn_sched_barrier(0);

        // ---- MFMA over K=256: frags read fp32 (swizzled), cvt->bf16 in-reg ----
        f32x4 acc[2][2];
        #pragma unroll
        for (int mi = 0; mi < 2; ++mi)
            #pragma unroll
            for (int ci = 0; ci < 2; ++ci) acc[mi][ci] = (f32x4){0.f, 0.f, 0.f, 0.f};

        __builtin_amdgcn_s_setprio(1);
        #pragma unroll
        for (int ks = 0; ks < 8; ++ks) {
            const int kk = ks * 32 + quad * 8;
            #pragma unroll
            for (int mi = 0; mi < 2; ++mi) {
                const int row = mi * 16 + l16;     // row&7 == l16&7 -> sxA
                float4 h0 = *reinterpret_cast<const float4*>(&xsb[row * CQ + (kk ^ sxA)]);
                float4 h1 = *reinterpret_cast<const float4*>(&xsb[row * CQ + ((kk + 4) ^ sxA)]);
                ushort2 p0 = pk2(h0.x, h0.y), p1 = pk2(h0.z, h0.w);
                ushort2 p2 = pk2(h1.x, h1.y), p3 = pk2(h1.z, h1.w);
                bf16x8 a = (bf16x8){ (short)p0.x, (short)p0.y, (short)p1.x, (short)p1.y,
                                     (short)p2.x, (short)p2.y, (short)p3.x, (short)p3.y };
                acc[mi][0] = __builtin_amdgcn_mfma_f32_16x16x32_bf16(a, Bf0[ks], acc[mi][0], 0, 0, 0);
                acc[mi][1] = __builtin_amdgcn_mfma_f32_16x16x32_bf16(a, Bf1[ks], acc[mi][1], 0, 0, 0);
            }
        }
        __builtin_amdgcn_s_setprio(0);

        // ---- phase B: e = exp(q); accumulate partials (x read fp32) ----
        const float* vt = vsm + (size_t)(i * RT) * 3;
        #pragma unroll
        for (int mi = 0; mi < 2; ++mi) {
            const int rbase = mi * 16 + quad * 4;
            float v0[4], v1[4], v2[4];
            #pragma unroll
            for (int r = 0; r < 4; ++r) {
                v0[r] = vt[(rbase + r) * 3 + 0];
                v1[r] = vt[(rbase + r) * 3 + 1];
                v2[r] = vt[(rbase + r) * 3 + 2];
            }
            #pragma unroll
            for (int ci = 0; ci < 2; ++ci) {
                const int xc = w * 32 + ci * 16 + l16;
                #pragma unroll
                for (int r = 0; r < 4; ++r) {
                    const int row = rbase + r;
                    float e = __expf(acc[mi][ci][r]);
                    float xv = xsb[row * CQ + (xc ^ ((row & 7) << 2))];
                    rZ[ci] += e;
                    float p = e * xv;
                    rS0[ci] = fmaf(p, v0[r], rS0[ci]);
                    rS1[ci] = fmaf(p, v1[r], rS1[ci]);
                    rS2[ci] = fmaf(p, v2[r], rS2[ci]);
                }
            }
        }

        // ---- tile boundary: drain staging, sync, swap ----
        __builtin_amdgcn_sched_barrier(0);
        asm volatile("s_waitcnt vmcnt(0)" ::: "memory");
        __builtin_amdgcn_sched_barrier(0);
        __builtin_amdgcn_s_barrier();
        __builtin_amdgcn_sched_barrier(0);
    }

    // ---- reduce over quads and ONE atomicAdd per col per block ----
    #pragma unroll
    for (int ci = 0; ci < 2; ++ci) {
        float z = rZ[ci], s0 = rS0[ci], s1 = rS1[ci], s2 = rS2[ci];
        #pragma unroll
        for (int off = 16; off < 64; off <<= 1) {
            z  += __shfl_xor(z,  off);
            s0 += __shfl_xor(s0, off);
            s1 += __shfl_xor(s1, off);
            s2 += __shfl_xor(s2, off);
        }
        if (quad == 0) {
            const int col = w * 32 + ci * 16 + l16;
            float* p = ws + ((size_t)bg * CQ + col) * 4;
            atomicAdd(&p[0], z);
            atomicAdd(&p[1], s0);
            atomicAdd(&p[2], s1);
            atomicAdd(&p[3], s2);
        }
    }
}

// ---- kernel 3: out[bg][o][d] = sum_c Wvn[o][c] * S[bg][c][d] / Z[bg][c] ----
__global__ __launch_bounds__(256, 4)
void vn_linear(const float* __restrict__ ws, const float* __restrict__ Wvn,
               float* __restrict__ out) {
    __shared__ float Tsm[CQ][3];
    const int bg = blockIdx.x, t = threadIdx.x;
    {
        f32x4 z4 = *reinterpret_cast<const f32x4*>(ws + ((size_t)bg * CQ + t) * 4);
        float inv = 1.f / z4[0];
        Tsm[t][0] = z4[1] * inv;
        Tsm[t][1] = z4[2] * inv;
        Tsm[t][2] = z4[3] * inv;
    }
    __syncthreads();
    const float* wr = Wvn + (size_t)t * CQ;
    float a0 = 0.f, a1 = 0.f, a2 = 0.f;
    #pragma unroll
    for (int c = 0; c < CQ; c += 4) {
        float4 w4 = *reinterpret_cast<const float4*>(wr + c);
        a0 += w4.x * Tsm[c + 0][0] + w4.y * Tsm[c + 1][0]
            + w4.z * Tsm[c + 2][0] + w4.w * Tsm[c + 3][0];
        a1 += w4.x * Tsm[c + 0][1] + w4.y * Tsm[c + 1][1]
            + w4.z * Tsm[c + 2][1] + w4.w * Tsm[c + 3][1];
        a2 += w4.x * Tsm[c + 0][2] + w4.y * Tsm[c + 1][2]
            + w4.z * Tsm[c + 2][2] + w4.w * Tsm[c + 3][2];
    }
    float* op = out + ((size_t)bg * CQ + t) * 3;
    op[0] = a0; op[1] = a1; op[2] = a2;
}

extern "C" void kernel_launch(void* const* d_in, const int* in_sizes, int n_in,
                              void* d_out, int out_size, void* d_ws, size_t ws_size,
                              hipStream_t stream) {
    const float* x   = (const float*)d_in[0];  // [8,16,1024,256]
    const float* vs  = (const float*)d_in[1];  // [8,16,1,1024,3]
    const float* Wfc = (const float*)d_in[2];  // [256,256]
    // d_in[3] = b_fc: constant along softmax axis n -> no effect, unused
    const float* Wvn = (const float*)d_in[4];  // [256,256]
    float* out = (float*)d_out;                // [8,16,256,3]
    float* ws  = (float*)d_ws;                 // 512 KB partials + 128 KB bf16 Wfc

    ushort* WbT = (ushort*)(ws + WB_OFF);

    (void)hipMemsetAsync(ws, 0, (size_t)128 * CQ * 4 * sizeof(float), stream);
    wfc_cvt<<<dim3(64), dim3(256), 0, stream>>>(Wfc, WbT);
    attn_pool_partial<<<dim3(512), dim3(512), 0, stream>>>(x, vs, WbT, ws);
    vn_linear<<<dim3(128), dim3(256), 0, stream>>>(ws, Wvn, out);
}

// Round 9
// 221.089 us; speedup vs baseline: 1.6680x; 1.4193x over previous
//
#include <hip/hip_runtime.h>
#include <hip/hip_bf16.h>

// B=8,G=16,N=1024,C=256.
// R14: R13 with the register-cap bug fixed.
//  R12/R13 both compiled to EXACTLY 64 VGPRs + scratch spill: the 2nd
//  __launch_bounds__ arg behaves as CUDA min-blocks/CU here, so (512,4)
//  meant 2048 thr/CU -> 64-reg cap; every 64-reg B-fragment design since
//  R10 was silently sunk (R10/R11, VGPR=48) or spilled (R12/R13, WRITE_SIZE
//  334/86 MB). Fix: __launch_bounds__(512, 2) -> 1024 thr/CU -> 128-reg cap.
//  Structure unchanged from R13 (passing, absmax 2.7e-3):
//   512 persistent blocks (2/CU) x 512 thr; 1 bg x 8 tiles of 32 rows each.
//   x staged HBM->LDS via global_load_lds (fp32, zero staging regs),
//   double-buffered; next tile issued before current tile's compute;
//   one vmcnt-drain + barrier per tile. B-frags loaded once, amortized 8x.
// wfc_cvt / vn_linear / ws layout unchanged (passing since R7).

#define NQ 1024
#define CQ 256
#define RT 32            // rows per tile
#define TILES 8          // tiles per block (8*32 = 256 rows/block)
#define WB_OFF 131072    // ws float offset of bf16 Wfc (after 512 KB partials)

typedef __attribute__((ext_vector_type(8))) short bf16x8;
typedef __attribute__((ext_vector_type(4))) float f32x4;

__device__ __forceinline__ ushort2 pk2(float a, float b) {
    __hip_bfloat162 h = __float22bfloat162_rn(make_float2(a, b));  // v_cvt_pk_bf16_f32
    ushort2 r;
    __builtin_memcpy(&r, &h, sizeof(r));
    return r;
}

// async 16B HBM->LDS; per-lane global src, wave-uniform LDS base (+lane*16 by HW)
__device__ __forceinline__ void gload16(const float* g, float* l) {
    __builtin_amdgcn_global_load_lds(
        (const __attribute__((address_space(1))) unsigned int*)g,
        (__attribute__((address_space(3))) unsigned int*)l, 16, 0, 0);
}

// ---- kernel 1: Wfc fp32 -> bf16 fragment-major WbT[k>>3][col][k&7] ----
__global__ __launch_bounds__(256)
void wfc_cvt(const float* __restrict__ Wfc, ushort* __restrict__ WbT) {
    const int i = blockIdx.x * 256 + threadIdx.x;   // 16384 threads x 4 floats
    const int o = i >> 6;            // output col (Wfc row) 0..255
    const int k4 = (i & 63) * 4;     // k start 0..252
    float4 v = *reinterpret_cast<const float4*>(Wfc + (size_t)o * CQ + k4);
    ushort2 a0 = pk2(v.x, v.y), a1 = pk2(v.z, v.w);
    ushort4 pk = { a0.x, a0.y, a1.x, a1.y };
    *reinterpret_cast<ushort4*>(WbT + ((size_t)(k4 >> 3) * CQ + o) * 8 + (k4 & 7)) = pk;
}

// ---- kernel 2: fused q=x@Wfc^T, e=exp(q), partial Z/S accumulation ----
__global__ __launch_bounds__(512, 2)
void attn_pool_partial(const float* __restrict__ x, const float* __restrict__ vs,
                       const ushort* __restrict__ WbT, float* __restrict__ ws) {
    __shared__ __align__(16) float xsf[2][RT * CQ];     // 2 x 32 KB, fp32, swizzled cols
    __shared__ __align__(16) float vsm[TILES * RT * 3]; // 3 KB: whole slab's v

    const int t = threadIdx.x;                     // 0..511
    const int id = blockIdx.x;                     // 0..511
    const int bg = id >> 2;
    const int ntg = id & 3;
    const int nb = ntg * (TILES * RT);             // block's 256-row slab

    const int w = t >> 6, lane = t & 63;
    const int quad = lane >> 4, l16 = lane & 15;
    const int sxA = (l16 & 7) << 2;                // fragment-read swizzle (elems)

    const float* xb = x + (size_t)bg * NQ * CQ;
    const float* vb = vs + (size_t)bg * NQ * 3;

    // ---- prologue group 1: B-fragments (L2-hot, live all block) ----
    bf16x8 Bf0[8], Bf1[8];
    const int bcol0 = w * 32 + l16;
    #pragma unroll
    for (int ks = 0; ks < 8; ++ks) {
        const size_t fo = (size_t)(ks * 4 + quad) * (CQ * 8);
        Bf0[ks] = *reinterpret_cast<const bf16x8*>(WbT + fo + (size_t)bcol0 * 8);
        Bf1[ks] = *reinterpret_cast<const bf16x8*>(WbT + fo + (size_t)(bcol0 + 16) * 8);
    }
    __builtin_amdgcn_sched_barrier(0);

    // ---- prologue group 2: v slab (256 rows x 3 = 768 floats) ----
    const bool vload = (t < 192);
    float4 vreg;
    if (vload) vreg = reinterpret_cast<const float4*>(vb + (size_t)nb * 3)[t];
    __builtin_amdgcn_sched_barrier(0);

    // ---- prologue group 3: stage tile 0 (async, no regs) ----
    #pragma unroll
    for (int p = 0; p < 4; ++p) {
        const int row = p * 8 + w;
        gload16(xb + (size_t)(nb + row) * CQ + (((lane * 4) ^ (w << 2))),
                &xsf[0][row * CQ]);
    }
    __builtin_amdgcn_sched_barrier(0);
    if (vload) reinterpret_cast<float4*>(vsm)[t] = vreg;
    __builtin_amdgcn_sched_barrier(0);
    asm volatile("s_waitcnt vmcnt(0) lgkmcnt(0)" ::: "memory");
    __builtin_amdgcn_sched_barrier(0);
    __builtin_amdgcn_s_barrier();
    __builtin_amdgcn_sched_barrier(0);

    // running partials across all 8 tiles
    float rZ[2] = {0.f, 0.f}, rS0[2] = {0.f, 0.f}, rS1[2] = {0.f, 0.f}, rS2[2] = {0.f, 0.f};

    for (int i = 0; i < TILES; ++i) {
        const int cur = i & 1;
        const float* xsb = xsf[cur];

        // ---- issue next tile's staging (flies under this tile's compute) ----
        if (i < TILES - 1) {
            const size_t gr = (size_t)(nb + (i + 1) * RT);
            float* dst = xsf[cur ^ 1];
            #pragma unroll
            for (int p = 0; p < 4; ++p) {
                const int row = p * 8 + w;
                gload16(xb + (gr + row) * CQ + (((lane * 4) ^ (w << 2))),
                        dst + row * CQ);
            }
        }
        __builtin_amdgcn_sched_barrier(0);

        // ---- MFMA over K=256: frags read fp32 (swizzled), cvt->bf16 in-reg ----
        f32x4 acc[2][2];
        #pragma unroll
        for (int mi = 0; mi < 2; ++mi)
            #pragma unroll
            for (int ci = 0; ci < 2; ++ci) acc[mi][ci] = (f32x4){0.f, 0.f, 0.f, 0.f};

        __builtin_amdgcn_s_setprio(1);
        #pragma unroll
        for (int ks = 0; ks < 8; ++ks) {
            const int kk = ks * 32 + quad * 8;
            #pragma unroll
            for (int mi = 0; mi < 2; ++mi) {
                const int row = mi * 16 + l16;     // row&7 == l16&7 -> sxA
                float4 h0 = *reinterpret_cast<const float4*>(&xsb[row * CQ + (kk ^ sxA)]);
                float4 h1 = *reinterpret_cast<const float4*>(&xsb[row * CQ + ((kk + 4) ^ sxA)]);
                ushort2 p0 = pk2(h0.x, h0.y), p1 = pk2(h0.z, h0.w);
                ushort2 p2 = pk2(h1.x, h1.y), p3 = pk2(h1.z, h1.w);
                bf16x8 a = (bf16x8){ (short)p0.x, (short)p0.y, (short)p1.x, (short)p1.y,
                                     (short)p2.x, (short)p2.y, (short)p3.x, (short)p3.y };
                acc[mi][0] = __builtin_amdgcn_mfma_f32_16x16x32_bf16(a, Bf0[ks], acc[mi][0], 0, 0, 0);
                acc[mi][1] = __builtin_amdgcn_mfma_f32_16x16x32_bf16(a, Bf1[ks], acc[mi][1], 0, 0, 0);
            }
        }
        __builtin_amdgcn_s_setprio(0);

        // ---- phase B: e = exp(q); accumulate partials (x read fp32) ----
        const float* vt = vsm + (size_t)(i * RT) * 3;
        #pragma unroll
        for (int mi = 0; mi < 2; ++mi) {
            const int rbase = mi * 16 + quad * 4;
            float v0[4], v1[4], v2[4];
            #pragma unroll
            for (int r = 0; r < 4; ++r) {
                v0[r] = vt[(rbase + r) * 3 + 0];
                v1[r] = vt[(rbase + r) * 3 + 1];
                v2[r] = vt[(rbase + r) * 3 + 2];
            }
            #pragma unroll
            for (int ci = 0; ci < 2; ++ci) {
                const int xc = w * 32 + ci * 16 + l16;
                #pragma unroll
                for (int r = 0; r < 4; ++r) {
                    const int row = rbase + r;
                    float e = __expf(acc[mi][ci][r]);
                    float xv = xsb[row * CQ + (xc ^ ((row & 7) << 2))];
                    rZ[ci] += e;
                    float p = e * xv;
                    rS0[ci] = fmaf(p, v0[r], rS0[ci]);
                    rS1[ci] = fmaf(p, v1[r], rS1[ci]);
                    rS2[ci] = fmaf(p, v2[r], rS2[ci]);
                }
            }
        }

        // ---- tile boundary: drain staging, sync, swap ----
        __builtin_amdgcn_sched_barrier(0);
        asm volatile("s_waitcnt vmcnt(0)" ::: "memory");
        __builtin_amdgcn_sched_barrier(0);
        __builtin_amdgcn_s_barrier();
        __builtin_amdgcn_sched_barrier(0);
    }

    // ---- reduce over quads and ONE atomicAdd per col per block ----
    #pragma unroll
    for (int ci = 0; ci < 2; ++ci) {
        float z = rZ[ci], s0 = rS0[ci], s1 = rS1[ci], s2 = rS2[ci];
        #pragma unroll
        for (int off = 16; off < 64; off <<= 1) {
            z  += __shfl_xor(z,  off);
            s0 += __shfl_xor(s0, off);
            s1 += __shfl_xor(s1, off);
            s2 += __shfl_xor(s2, off);
        }
        if (quad == 0) {
            const int col = w * 32 + ci * 16 + l16;
            float* p = ws + ((size_t)bg * CQ + col) * 4;
            atomicAdd(&p[0], z);
            atomicAdd(&p[1], s0);
            atomicAdd(&p[2], s1);
            atomicAdd(&p[3], s2);
        }
    }
}

// ---- kernel 3: out[bg][o][d] = sum_c Wvn[o][c] * S[bg][c][d] / Z[bg][c] ----
__global__ __launch_bounds__(256, 4)
void vn_linear(const float* __restrict__ ws, const float* __restrict__ Wvn,
               float* __restrict__ out) {
    __shared__ float Tsm[CQ][3];
    const int bg = blockIdx.x, t = threadIdx.x;
    {
        f32x4 z4 = *reinterpret_cast<const f32x4*>(ws + ((size_t)bg * CQ + t) * 4);
        float inv = 1.f / z4[0];
        Tsm[t][0] = z4[1] * inv;
        Tsm[t][1] = z4[2] * inv;
        Tsm[t][2] = z4[3] * inv;
    }
    __syncthreads();
    const float* wr = Wvn + (size_t)t * CQ;
    float a0 = 0.f, a1 = 0.f, a2 = 0.f;
    #pragma unroll
    for (int c = 0; c < CQ; c += 4) {
        float4 w4 = *reinterpret_cast<const float4*>(wr + c);
        a0 += w4.x * Tsm[c + 0][0] + w4.y * Tsm[c + 1][0]
            + w4.z * Tsm[c + 2][0] + w4.w * Tsm[c + 3][0];
        a1 += w4.x * Tsm[c + 0][1] + w4.y * Tsm[c + 1][1]
            + w4.z * Tsm[c + 2][1] + w4.w * Tsm[c + 3][1];
        a2 += w4.x * Tsm[c + 0][2] + w4.y * Tsm[c + 1][2]
            + w4.z * Tsm[c + 2][2] + w4.w * Tsm[c + 3][2];
    }
    float* op = out + ((size_t)bg * CQ + t) * 3;
    op[0] = a0; op[1] = a1; op[2] = a2;
}

extern "C" void kernel_launch(void* const* d_in, const int* in_sizes, int n_in,
                              void* d_out, int out_size, void* d_ws, size_t ws_size,
                              hipStream_t stream) {
    const float* x   = (const float*)d_in[0];  // [8,16,1024,256]
    const float* vs  = (const float*)d_in[1];  // [8,16,1,1024,3]
    const float* Wfc = (const float*)d_in[2];  // [256,256]
    // d_in[3] = b_fc: constant along softmax axis n -> no effect, unused
    const float* Wvn = (const float*)d_in[4];  // [256,256]
    float* out = (float*)d_out;                // [8,16,256,3]
    float* ws  = (float*)d_ws;                 // 512 KB partials + 128 KB bf16 Wfc

    ushort* WbT = (ushort*)(ws + WB_OFF);

    (void)hipMemsetAsync(ws, 0, (size_t)128 * CQ * 4 * sizeof(float), stream);
    wfc_cvt<<<dim3(64), dim3(256), 0, stream>>>(Wfc, WbT);
    attn_pool_partial<<<dim3(512), dim3(512), 0, stream>>>(x, vs, WbT, ws);
    vn_linear<<<dim3(128), dim3(256), 0, stream>>>(ws, Wvn, out);
}

// Round 10
// 216.718 us; speedup vs baseline: 1.7016x; 1.0202x over previous
//
#include <hip/hip_runtime.h>
#include <hip/hip_bf16.h>

// B=8,G=16,N=1024,C=256.
// R15: convert-once-per-tile pipeline (R14 + LDS->LDS cvt stage).
//  R14's binding resource was the LDS pipe + 8-way duplicated cvt: every wave
//  re-read the fp32 tile as 2x ds_read_b128 per A-frag and re-ran 64 cvt_pk
//  per tile on shared data (~26 us LDS + dup VALU). Now: gload_lds lands fp32
//  in `land` (32 KB); one cooperative cvt pass (8 cvt_pk/thread/tile) writes a
//  compact bf16 tile with XOR swizzle (byte ^= (row&7)<<4, T2); A-frags become
//  one ds_read_b128, phase-B reads u16. 2 barriers/tile; gloads still fly
//  under the whole compute phase. LDS 67 KB -> 2 blocks/CU. (512,2) reg cap.
// wfc_cvt / vn_linear / ws layout unchanged (passing since R7).

#define NQ 1024
#define CQ 256
#define RT 32            // rows per tile
#define TILES 8          // tiles per block (8*32 = 256 rows/block)
#define WB_OFF 131072    // ws float offset of bf16 Wfc (after 512 KB partials)

typedef __attribute__((ext_vector_type(8))) short bf16x8;
typedef __attribute__((ext_vector_type(4))) float f32x4;

__device__ __forceinline__ ushort2 pk2(float a, float b) {
    __hip_bfloat162 h = __float22bfloat162_rn(make_float2(a, b));  // v_cvt_pk_bf16_f32
    ushort2 r;
    __builtin_memcpy(&r, &h, sizeof(r));
    return r;
}
__device__ __forceinline__ float bf2f(ushort h) {
    union { unsigned u; float f; } v; v.u = ((unsigned)h) << 16;
    return v.f;
}

// async 16B HBM->LDS; per-lane global src, wave-uniform LDS base (+lane*16 by HW)
__device__ __forceinline__ void gload16(const float* g, float* l) {
    __builtin_amdgcn_global_load_lds(
        (const __attribute__((address_space(1))) unsigned int*)g,
        (__attribute__((address_space(3))) unsigned int*)l, 16, 0, 0);
}

// lgkm-only barrier: LDS writes visible, global loads stay in flight.
__device__ __forceinline__ void bar_lgkm() {
    __builtin_amdgcn_sched_barrier(0);
    asm volatile("s_waitcnt lgkmcnt(0)" ::: "memory");
    __builtin_amdgcn_sched_barrier(0);
    __builtin_amdgcn_s_barrier();
    __builtin_amdgcn_sched_barrier(0);
}

// ---- kernel 1: Wfc fp32 -> bf16 fragment-major WbT[k>>3][col][k&7] ----
__global__ __launch_bounds__(256)
void wfc_cvt(const float* __restrict__ Wfc, ushort* __restrict__ WbT) {
    const int i = blockIdx.x * 256 + threadIdx.x;   // 16384 threads x 4 floats
    const int o = i >> 6;            // output col (Wfc row) 0..255
    const int k4 = (i & 63) * 4;     // k start 0..252
    float4 v = *reinterpret_cast<const float4*>(Wfc + (size_t)o * CQ + k4);
    ushort2 a0 = pk2(v.x, v.y), a1 = pk2(v.z, v.w);
    ushort4 pk = { a0.x, a0.y, a1.x, a1.y };
    *reinterpret_cast<ushort4*>(WbT + ((size_t)(k4 >> 3) * CQ + o) * 8 + (k4 & 7)) = pk;
}

// ---- kernel 2: fused q=x@Wfc^T, e=exp(q), partial Z/S accumulation ----
__global__ __launch_bounds__(512, 2)
void attn_pool_partial(const float* __restrict__ x, const float* __restrict__ vs,
                       const ushort* __restrict__ WbT, float* __restrict__ ws) {
    __shared__ __align__(16) float land[RT * CQ];        // 32 KB fp32 landing
    __shared__ __align__(16) char  bx[2][RT * 512];      // 2 x 16 KB bf16 tiles (swizzled)
    __shared__ __align__(16) float vsm[TILES * RT * 3];  // 3 KB: whole slab's v

    const int t = threadIdx.x;                     // 0..511
    const int id = blockIdx.x;                     // 0..511
    const int bg = id >> 2;
    const int ntg = id & 3;
    const int nb = ntg * (TILES * RT);             // block's 256-row slab

    const int w = t >> 6, lane = t & 63;
    const int quad = lane >> 4, l16 = lane & 15;

    const float* xb = x + (size_t)bg * NQ * CQ;
    const float* vb = vs + (size_t)bg * NQ * 3;

    // ---- prologue group 1: B-fragments (L2-hot, live all block) ----
    bf16x8 Bf0[8], Bf1[8];
    const int bcol0 = w * 32 + l16;
    #pragma unroll
    for (int ks = 0; ks < 8; ++ks) {
        const size_t fo = (size_t)(ks * 4 + quad) * (CQ * 8);
        Bf0[ks] = *reinterpret_cast<const bf16x8*>(WbT + fo + (size_t)bcol0 * 8);
        Bf1[ks] = *reinterpret_cast<const bf16x8*>(WbT + fo + (size_t)(bcol0 + 16) * 8);
    }
    __builtin_amdgcn_sched_barrier(0);

    // ---- prologue group 2: v slab (256 rows x 3 = 768 floats = 192 float4) ----
    const bool vload = (t < 192);
    float4 vreg;
    if (vload) vreg = reinterpret_cast<const float4*>(vb + (size_t)nb * 3)[t];
    __builtin_amdgcn_sched_barrier(0);

    // ---- prologue group 3: stage tile 0 fp32 (async, no regs) ----
    #pragma unroll
    for (int p = 0; p < 4; ++p) {
        const int row = p * 8 + w;                 // wave-uniform row
        gload16(xb + (size_t)(nb + row) * CQ + lane * 4, &land[row * CQ]);
    }
    __builtin_amdgcn_sched_barrier(0);
    asm volatile("s_waitcnt vmcnt(0)" ::: "memory");
    __builtin_amdgcn_sched_barrier(0);
    if (vload) reinterpret_cast<float4*>(vsm)[t] = vreg;
    bar_lgkm();    // land + vsm visible (gload drained above, vsm via lgkm)

    // ---- cvt tile 0 -> bx[0] ----
    {
        char* dst = bx[0];
        #pragma unroll
        for (int p = 0; p < 4; ++p) {
            const int row = p * 8 + w;
            float4 v4 = *reinterpret_cast<const float4*>(&land[row * CQ + lane * 4]);
            ushort2 a0 = pk2(v4.x, v4.y), a1 = pk2(v4.z, v4.w);
            ushort4 pk = { a0.x, a0.y, a1.x, a1.y };
            *reinterpret_cast<ushort4*>(dst + row * 512 + ((lane * 8) ^ ((row & 7) << 4))) = pk;
        }
    }
    bar_lgkm();

    // running partials across all 8 tiles
    float rZ[2] = {0.f, 0.f}, rS0[2] = {0.f, 0.f}, rS1[2] = {0.f, 0.f}, rS2[2] = {0.f, 0.f};

    for (int i = 0; i < TILES; ++i) {
        const char* bxp = bx[i & 1];

        // ---- issue next tile's fp32 staging (flies under this tile's compute) ----
        if (i < TILES - 1) {
            const int tb = nb + (i + 1) * RT;
            #pragma unroll
            for (int p = 0; p < 4; ++p) {
                const int row = p * 8 + w;
                gload16(xb + (size_t)(tb + row) * CQ + lane * 4, &land[row * CQ]);
            }
        }
        __builtin_amdgcn_sched_barrier(0);

        // ---- MFMA over K=256: A-frag = one b128 from swizzled bf16 tile ----
        f32x4 acc[2][2];
        #pragma unroll
        for (int mi = 0; mi < 2; ++mi)
            #pragma unroll
            for (int ci = 0; ci < 2; ++ci) acc[mi][ci] = (f32x4){0.f, 0.f, 0.f, 0.f};

        __builtin_amdgcn_s_setprio(1);
        #pragma unroll
        for (int ks = 0; ks < 8; ++ks) {
            const int kkb = ks * 64 + quad * 16;   // colbyte of this frag
            #pragma unroll
            for (int mi = 0; mi < 2; ++mi) {
                const int row = mi * 16 + l16;
                bf16x8 a = *reinterpret_cast<const bf16x8*>(
                    bxp + row * 512 + (kkb ^ ((row & 7) << 4)));
                acc[mi][0] = __builtin_amdgcn_mfma_f32_16x16x32_bf16(a, Bf0[ks], acc[mi][0], 0, 0, 0);
                acc[mi][1] = __builtin_amdgcn_mfma_f32_16x16x32_bf16(a, Bf1[ks], acc[mi][1], 0, 0, 0);
            }
        }
        __builtin_amdgcn_s_setprio(0);

        // ---- phase B: e = exp(q); accumulate partials (x read as bf16 u16) ----
        const float* vt = vsm + (size_t)(i * RT) * 3;
        #pragma unroll
        for (int mi = 0; mi < 2; ++mi) {
            const int rbase = mi * 16 + quad * 4;
            float v0[4], v1[4], v2[4];
            #pragma unroll
            for (int r = 0; r < 4; ++r) {
                v0[r] = vt[(rbase + r) * 3 + 0];
                v1[r] = vt[(rbase + r) * 3 + 1];
                v2[r] = vt[(rbase + r) * 3 + 2];
            }
            #pragma unroll
            for (int ci = 0; ci < 2; ++ci) {
                const int xc = w * 32 + ci * 16 + l16;
                #pragma unroll
                for (int r = 0; r < 4; ++r) {
                    const int row = rbase + r;
                    float e = __expf(acc[mi][ci][r]);
                    ushort h = *reinterpret_cast<const ushort*>(
                        bxp + row * 512 + ((xc * 2) ^ ((row & 7) << 4)));
                    float xv = bf2f(h);
                    rZ[ci] += e;
                    float p = e * xv;
                    rS0[ci] = fmaf(p, v0[r], rS0[ci]);
                    rS1[ci] = fmaf(p, v1[r], rS1[ci]);
                    rS2[ci] = fmaf(p, v2[r], rS2[ci]);
                }
            }
        }

        // ---- tile boundary: drain staging, sync, cvt next tile, sync ----
        __builtin_amdgcn_sched_barrier(0);
        asm volatile("s_waitcnt vmcnt(0)" ::: "memory");
        __builtin_amdgcn_sched_barrier(0);
        __builtin_amdgcn_s_barrier();
        __builtin_amdgcn_sched_barrier(0);

        if (i < TILES - 1) {
            char* dst = bx[(i + 1) & 1];
            #pragma unroll
            for (int p = 0; p < 4; ++p) {
                const int row = p * 8 + w;
                float4 v4 = *reinterpret_cast<const float4*>(&land[row * CQ + lane * 4]);
                ushort2 a0 = pk2(v4.x, v4.y), a1 = pk2(v4.z, v4.w);
                ushort4 pk = { a0.x, a0.y, a1.x, a1.y };
                *reinterpret_cast<ushort4*>(dst + row * 512 + ((lane * 8) ^ ((row & 7) << 4))) = pk;
            }
            bar_lgkm();
        }
    }

    // ---- reduce over quads and ONE atomicAdd per col per block ----
    #pragma unroll
    for (int ci = 0; ci < 2; ++ci) {
        float z = rZ[ci], s0 = rS0[ci], s1 = rS1[ci], s2 = rS2[ci];
        #pragma unroll
        for (int off = 16; off < 64; off <<= 1) {
            z  += __shfl_xor(z,  off);
            s0 += __shfl_xor(s0, off);
            s1 += __shfl_xor(s1, off);
            s2 += __shfl_xor(s2, off);
        }
        if (quad == 0) {
            const int col = w * 32 + ci * 16 + l16;
            float* p = ws + ((size_t)bg * CQ + col) * 4;
            atomicAdd(&p[0], z);
            atomicAdd(&p[1], s0);
            atomicAdd(&p[2], s1);
            atomicAdd(&p[3], s2);
        }
    }
}

// ---- kernel 3: out[bg][o][d] = sum_c Wvn[o][c] * S[bg][c][d] / Z[bg][c] ----
__global__ __launch_bounds__(256, 4)
void vn_linear(const float* __restrict__ ws, const float* __restrict__ Wvn,
               float* __restrict__ out) {
    __shared__ float Tsm[CQ][3];
    const int bg = blockIdx.x, t = threadIdx.x;
    {
        f32x4 z4 = *reinterpret_cast<const f32x4*>(ws + ((size_t)bg * CQ + t) * 4);
        float inv = 1.f / z4[0];
        Tsm[t][0] = z4[1] * inv;
        Tsm[t][1] = z4[2] * inv;
        Tsm[t][2] = z4[3] * inv;
    }
    __syncthreads();
    const float* wr = Wvn + (size_t)t * CQ;
    float a0 = 0.f, a1 = 0.f, a2 = 0.f;
    #pragma unroll
    for (int c = 0; c < CQ; c += 4) {
        float4 w4 = *reinterpret_cast<const float4*>(wr + c);
        a0 += w4.x * Tsm[c + 0][0] + w4.y * Tsm[c + 1][0]
            + w4.z * Tsm[c + 2][0] + w4.w * Tsm[c + 3][0];
        a1 += w4.x * Tsm[c + 0][1] + w4.y * Tsm[c + 1][1]
            + w4.z * Tsm[c + 2][1] + w4.w * Tsm[c + 3][1];
        a2 += w4.x * Tsm[c + 0][2] + w4.y * Tsm[c + 1][2]
            + w4.z * Tsm[c + 2][2] + w4.w * Tsm[c + 3][2];
    }
    float* op = out + ((size_t)bg * CQ + t) * 3;
    op[0] = a0; op[1] = a1; op[2] = a2;
}

extern "C" void kernel_launch(void* const* d_in, const int* in_sizes, int n_in,
                              void* d_out, int out_size, void* d_ws, size_t ws_size,
                              hipStream_t stream) {
    const float* x   = (const float*)d_in[0];  // [8,16,1024,256]
    const float* vs  = (const float*)d_in[1];  // [8,16,1,1024,3]
    const float* Wfc = (const float*)d_in[2];  // [256,256]
    // d_in[3] = b_fc: constant along softmax axis n -> no effect, unused
    const float* Wvn = (const float*)d_in[4];  // [256,256]
    float* out = (float*)d_out;                // [8,16,256,3]
    float* ws  = (float*)d_ws;                 // 512 KB partials + 128 KB bf16 Wfc

    ushort* WbT = (ushort*)(ws + WB_OFF);

    (void)hipMemsetAsync(ws, 0, (size_t)128 * CQ * 4 * sizeof(float), stream);
    wfc_cvt<<<dim3(64), dim3(256), 0, stream>>>(Wfc, WbT);
    attn_pool_partial<<<dim3(512), dim3(512), 0, stream>>>(x, vs, WbT, ws);
    vn_linear<<<dim3(128), dim3(256), 0, stream>>>(ws, Wvn, out);
}